// Round 7
// baseline (220.678 us; speedup 1.0000x reference)
//
#include <hip/hip_runtime.h>
#include <math.h>

#define N_NODES 32768
#define NPG 512
#define NGRAPH 64
#define KKEEP 256
#define CAP 64

typedef __attribute__((ext_vector_type(8))) short short8;
typedef __attribute__((ext_vector_type(4))) float f32x4;

__device__ __forceinline__ unsigned short f2bf(float v) {
  unsigned u = __builtin_bit_cast(unsigned, v);
  u = (u + 0x7FFFu + ((u >> 16) & 1u)) >> 16;
  return (unsigned short)u;
}
__device__ __forceinline__ float bf2f(unsigned short u) {
  unsigned v = ((unsigned)u) << 16;
  return __builtin_bit_cast(float, v);
}

__device__ __forceinline__ void async_cp16(unsigned short* l, const unsigned short* g) {
  __builtin_amdgcn_global_load_lds(
      (const __attribute__((address_space(1))) unsigned int*)g,
      (__attribute__((address_space(3))) unsigned int*)l, 16, 0, 0);
}

// raw barrier: memory-clobber asm (blocks IR-level motion) + sched_barrier
// (blocks MIR-level motion, rule 18).  No implicit vmcnt(0) drain.
__device__ __forceinline__ void block_barrier() {
  __builtin_amdgcn_sched_barrier(0);
  asm volatile("s_barrier" ::: "memory");
  __builtin_amdgcn_sched_barrier(0);
}
__device__ __forceinline__ void wait_all() {
  asm volatile("s_waitcnt vmcnt(0) lgkmcnt(0)" ::: "memory");
  __builtin_amdgcn_sched_barrier(0);
}

// ---- W split-3 bf16 convert (tiny pre-kernel; bit-identical to baseline) ----
__global__ __launch_bounds__(256) void k_conv(
    const float* __restrict__ W,
    unsigned short* __restrict__ wth, unsigned short* __restrict__ wtl,
    unsigned short* __restrict__ wtll) {
  const int t = threadIdx.x;
  int n = blockIdx.x * 4 + (t >> 6);         // output col of W
  int k = (t & 63) * 4;
  unsigned short hb[4], lb[4], qb[4];
#pragma unroll
  for (int j = 0; j < 4; j++) {
    float v = W[(size_t)(k + j) * 256 + n];
    unsigned short hh = f2bf(v);
    float e1 = v - bf2f(hh);                 // exact
    unsigned short ll = f2bf(e1);
    float e2 = e1 - bf2f(ll);                // exact
    hb[j] = hh; lb[j] = ll; qb[j] = f2bf(e2);
  }
  *(uint2*)&wth[(size_t)n * 256 + k] = *(uint2*)&hb[0];
  *(uint2*)&wtl[(size_t)n * 256 + k] = *(uint2*)&lb[0];
  *(uint2*)&wtll[(size_t)n * 256 + k] = *(uint2*)&qb[0];
}

// ---- merged: MFMA split-3 GEMM (blocks 0..511, 128x128, 512 thr)
//      + edge bucketing (blocks 512..1535) ----
// A: NO LDS round-trip — each lane loads its own fragment rows directly from
// x (16-row x 128B segments, L2/L3-hot) and converts in registers with the
// identical f2bf split-3 math -> bit-identical MFMA operands.
// B: double-buffered LDS via global_load_lds, staged at TOP of iteration;
// ONE wait+barrier per kc.  LDS 48 KB (B only; epilogue aliases).
// h / a_src / a_dst are bit-identical to the round-0 verified kernel.
#define B_SZ 12288             // ushorts per B buffer (3 planes x 4096)
__global__ __launch_bounds__(512, 4) void k_gemm_hist(
    const float* __restrict__ x,
    const unsigned short* __restrict__ wth, const unsigned short* __restrict__ wtl,
    const unsigned short* __restrict__ wtll,
    const float* __restrict__ attS, const float* __restrict__ attD,
    float* __restrict__ h, float* __restrict__ a_src, float* __restrict__ a_dst,
    const int* __restrict__ ei, int E, int* __restrict__ cnt,
    unsigned short* __restrict__ nbr) {
  __shared__ unsigned short lds[24576];      // 48 KB
  const int t = threadIdx.x;
  const int bid = blockIdx.x;
  if (bid >= 512) {
    // edge bucketing: independent of GEMM, backfills behind it
    int e = (bid - 512) * 512 + t;
    if (e < E) {
      int s = ei[e];
      int d = ei[E + e];
      int slot = atomicAdd(&cnt[d], 1);
      if (slot < CAP) nbr[(size_t)d * CAP + slot] = (unsigned short)(s & (NPG - 1));
    }
    return;
  }
  // XCD pairing: both nh halves of an mb land on the same XCD (bid%8);
  // XCD c owns mb in [32c, 32c+32) -> A rows [4096c, 4096c+4096), matches k_agg.
  const int mb = (bid & 7) * 32 + (bid >> 4);
  const int nh = (bid >> 3) & 1;
  const int row0 = mb * 128;
  const int wid = t >> 6, lane = t & 63;
  const int q = lane >> 4, ln = lane & 15;
  const int wm = (wid >> 1) * 32, wn = (wid & 1) * 64;
  f32x4 acc[2][4] = {};

  // per-lane A row bases (fragment rows for mt=0,1)
  const float* xr0 = &x[(size_t)(row0 + wm + ln) * 256 + q * 8];
  const float* xr1 = &x[(size_t)(row0 + wm + 16 + ln) * 256 + q * 8];
  const size_t gb0 = (size_t)(nh * 128 + (t & 127)) * 256 + (t >> 7) * 8;

  // ---- prologue: stage B(kc=0), load A(kc=0) ----
  async_cp16(&lds[0 * 4096 + t * 8], &wth[gb0]);
  async_cp16(&lds[1 * 4096 + t * 8], &wtl[gb0]);
  async_cp16(&lds[2 * 4096 + t * 8], &wtll[gb0]);
  float4 cf0 = *(const float4*)(xr0);
  float4 cf1 = *(const float4*)(xr0 + 4);
  float4 cf2 = *(const float4*)(xr1);
  float4 cf3 = *(const float4*)(xr1 + 4);
  wait_all();
  block_barrier();

  for (int kc = 0; kc < 8; kc++) {
    const int cur = kc & 1;
    // issue next B stage + next A loads FIRST (in flight across MFMA phase)
    float4 nf0, nf1, nf2, nf3;
    if (kc < 7) {
      const int k1 = (kc + 1) * 32;
      unsigned short* bb = &lds[(cur ^ 1) * B_SZ];
      async_cp16(&bb[0 * 4096 + t * 8], &wth[gb0 + k1]);
      async_cp16(&bb[1 * 4096 + t * 8], &wtl[gb0 + k1]);
      async_cp16(&bb[2 * 4096 + t * 8], &wtll[gb0 + k1]);
      nf0 = *(const float4*)(xr0 + k1);
      nf1 = *(const float4*)(xr0 + k1 + 4);
      nf2 = *(const float4*)(xr1 + k1);
      nf3 = *(const float4*)(xr1 + k1 + 4);
    }
    // convert A(kc) regs -> frags (identical split-3 math, identical order)
    short8 ah[2], al[2], aq[2];
#pragma unroll
    for (int mt = 0; mt < 2; mt++) {
      float ff[8];
      if (mt == 0) {
        ff[0] = cf0.x; ff[1] = cf0.y; ff[2] = cf0.z; ff[3] = cf0.w;
        ff[4] = cf1.x; ff[5] = cf1.y; ff[6] = cf1.z; ff[7] = cf1.w;
      } else {
        ff[0] = cf2.x; ff[1] = cf2.y; ff[2] = cf2.z; ff[3] = cf2.w;
        ff[4] = cf3.x; ff[5] = cf3.y; ff[6] = cf3.z; ff[7] = cf3.w;
      }
      unsigned short hs[8], ls[8], qs[8];
#pragma unroll
      for (int j = 0; j < 8; j++) {
        unsigned short hh = f2bf(ff[j]);
        float e1 = ff[j] - bf2f(hh);         // exact
        unsigned short ll = f2bf(e1);
        float e2 = e1 - bf2f(ll);            // exact
        hs[j] = hh; ls[j] = ll; qs[j] = f2bf(e2);
      }
      ah[mt] = *(const short8*)&hs[0];
      al[mt] = *(const short8*)&ls[0];
      aq[mt] = *(const short8*)&qs[0];
    }
    // MFMA phase on B[cur]
    const unsigned short* bc = &lds[cur * B_SZ];
#pragma unroll
    for (int nt = 0; nt < 4; nt++) {
      int r = wn + nt * 16 + ln;
      short8 bh = *(const short8*)&bc[0 * 4096 + (q * 128 + r) * 8];
      short8 bl = *(const short8*)&bc[1 * 4096 + (q * 128 + r) * 8];
      short8 bq = *(const short8*)&bc[2 * 4096 + (q * 128 + r) * 8];
#pragma unroll
      for (int mt = 0; mt < 2; mt++) {
        acc[mt][nt] = __builtin_amdgcn_mfma_f32_16x16x32_bf16(ah[mt], bh, acc[mt][nt], 0, 0, 0);
        acc[mt][nt] = __builtin_amdgcn_mfma_f32_16x16x32_bf16(ah[mt], bl, acc[mt][nt], 0, 0, 0);
        acc[mt][nt] = __builtin_amdgcn_mfma_f32_16x16x32_bf16(al[mt], bh, acc[mt][nt], 0, 0, 0);
        acc[mt][nt] = __builtin_amdgcn_mfma_f32_16x16x32_bf16(ah[mt], bq, acc[mt][nt], 0, 0, 0);
        acc[mt][nt] = __builtin_amdgcn_mfma_f32_16x16x32_bf16(al[mt], bl, acc[mt][nt], 0, 0, 0);
        acc[mt][nt] = __builtin_amdgcn_mfma_f32_16x16x32_bf16(aq[mt], bh, acc[mt][nt], 0, 0, 0);
      }
    }
    wait_all();                 // B(kc+1)+A(kc+1) landed; B[cur] reads done
    block_barrier();
    if (kc < 7) { cf0 = nf0; cf1 = nf1; cf2 = nf2; cf3 = nf3; }
  }

  // epilogue: store h; att partials via LDS transpose (aliased over staging).
  // XOR swizzle (ln^(q*4)) is bijective per row; read back in ln order ->
  // bit-identical sums to the round-0 epilogue.
  const int head = nh * 2 + (wid & 1);
  float sA[4], sD[4];
#pragma unroll
  for (int nt = 0; nt < 4; nt++) {
    int n = nh * 128 + wn + nt * 16 + ln;
    sA[nt] = attS[n];
    sD[nt] = attD[n];
  }
  float2* epi = (float2*)lds;   // [wid(8)][q(4)][row(8)][18] float2
#pragma unroll
  for (int mt = 0; mt < 2; mt++) {
#pragma unroll
    for (int reg = 0; reg < 4; reg++) {
      int m = row0 + wm + mt * 16 + q * 4 + reg;
      float ps = 0.f, pd = 0.f;
#pragma unroll
      for (int nt = 0; nt < 4; nt++) {
        float v = acc[mt][nt][reg];
        h[(size_t)m * 256 + nh * 128 + wn + nt * 16 + ln] = v;
        ps = fmaf(v, sA[nt], ps);
        pd = fmaf(v, sD[nt], pd);
      }
      epi[(((wid * 4 + q) * 8) + mt * 4 + reg) * 18 + (ln ^ (q * 4))] =
          make_float2(ps, pd);
    }
  }
  __syncthreads();
  if (lane < 32) {
    const int rr2 = lane & 7;                // mt*4+reg
    const int q2 = lane >> 3;                // row group's q
    const int base = (((wid * 4 + q2) * 8) + rr2) * 18;
    float ps = 0.f, pd = 0.f;
#pragma unroll
    for (int i = 0; i < 16; i++) {
      float2 v = epi[base + (i ^ (q2 * 4))];
      ps += v.x;
      pd += v.y;
    }
    int m = row0 + wm + (rr2 >> 2) * 16 + q2 * 4 + (rr2 & 3);
    a_src[m * 4 + head] = ps;
    a_dst[m * 4 + head] = pd;
  }
}

// ---- aggregation: softmax weights computed once, broadcast via LDS ----
__global__ __launch_bounds__(256) void k_agg(
    const float* __restrict__ h, const float* __restrict__ a_src,
    const float* __restrict__ a_dst, const int* __restrict__ cnt,
    const unsigned short* __restrict__ nbr, const float* __restrict__ bias,
    float* __restrict__ feat) {
  __shared__ float p_lds[4][68][4];
  __shared__ int s_lds[4][68];
  const int wv = threadIdx.x >> 6;
  const int lane = threadIdx.x & 63;
  int nb = (blockIdx.x & 7) * (N_NODES / 4 / 8) + (blockIdx.x >> 3);
  const int node = nb * 4 + wv;
  const int head = lane >> 4;
  const int li = lane & 15;
  const int c0 = lane * 4;
  const int base = node & ~(NPG - 1);
  const float ad = a_dst[node * 4 + head];
  int n = cnt[node];
  if (n > CAP) n = CAP;
  float e_reg[5];
  int srcs[5];
  int nit = 0;
  float m = -1e30f;
  for (int j = li; j <= n; j += 16) {
    int s = (j < n) ? base + (int)nbr[(size_t)node * CAP + j] : node;
    float e = a_src[s * 4 + head] + ad;
    e = (e > 0.f) ? e : 0.2f * e;
    srcs[nit] = s;
    e_reg[nit++] = e;
    m = fmaxf(m, e);
  }
#pragma unroll
  for (int d = 1; d < 16; d <<= 1) m = fmaxf(m, __shfl_xor(m, d, 16));
  float l = 0.f;
  for (int i = 0; i < nit; i++) {
    int j = li + i * 16;
    float p = __expf(e_reg[i] - m);
    l += p;
    p_lds[wv][j][head] = p;
    if (head == 0) s_lds[wv][j] = srcs[i];
  }
#pragma unroll
  for (int d = 1; d < 16; d <<= 1) l += __shfl_xor(l, d, 16);
  const float linv = 1.f / (l + 1e-16f);
  __builtin_amdgcn_s_waitcnt(0);
  float4 acc0 = make_float4(0.f, 0.f, 0.f, 0.f);
  float4 acc1 = make_float4(0.f, 0.f, 0.f, 0.f);
  int j = 0;
  for (; j + 1 <= n; j += 2) {
    float p0 = p_lds[wv][j][head];
    float p1 = p_lds[wv][j + 1][head];
    int s0 = s_lds[wv][j];
    int s1 = s_lds[wv][j + 1];
    float4 h0 = *(const float4*)&h[(size_t)s0 * 256 + c0];
    float4 h1 = *(const float4*)&h[(size_t)s1 * 256 + c0];
    acc0.x = fmaf(p0, h0.x, acc0.x); acc1.x = fmaf(p1, h1.x, acc1.x);
    acc0.y = fmaf(p0, h0.y, acc0.y); acc1.y = fmaf(p1, h1.y, acc1.y);
    acc0.z = fmaf(p0, h0.z, acc0.z); acc1.z = fmaf(p1, h1.z, acc1.z);
    acc0.w = fmaf(p0, h0.w, acc0.w); acc1.w = fmaf(p1, h1.w, acc1.w);
  }
  if (j <= n) {
    float p0 = p_lds[wv][j][head];
    int s0 = s_lds[wv][j];
    float4 h0 = *(const float4*)&h[(size_t)s0 * 256 + c0];
    acc0.x = fmaf(p0, h0.x, acc0.x);
    acc0.y = fmaf(p0, h0.y, acc0.y);
    acc0.z = fmaf(p0, h0.z, acc0.z);
    acc0.w = fmaf(p0, h0.w, acc0.w);
  }
  const float4 b4 = *(const float4*)&bias[c0];
  float4 o;
  o.x = fmaxf(fmaf(acc0.x + acc1.x, linv, b4.x), 0.f);
  o.y = fmaxf(fmaf(acc0.y + acc1.y, linv, b4.y), 0.f);
  o.z = fmaxf(fmaf(acc0.z + acc1.z, linv, b4.z), 0.f);
  o.w = fmaxf(fmaf(acc0.w + acc1.w, linv, b4.w), 0.f);
  *(float4*)&feat[(size_t)node * 256 + c0] = o;
}

// ---- BN stats ----
__global__ __launch_bounds__(256) void k_bn_partial(const float* __restrict__ feat,
                                                    double* __restrict__ psum,
                                                    double* __restrict__ psq) {
  const int c = threadIdx.x;
  const int r0 = blockIdx.x * 128;
  double s = 0.0, q = 0.0;
  for (int i = 0; i < 128; i++) {
    double v = (double)feat[(size_t)(r0 + i) * 256 + c];
    s += v;
    q += v * v;
  }
  psum[blockIdx.x * 256 + c] = s;
  psq[blockIdx.x * 256 + c] = q;
}

// cA/cB for output BN; sv[c]=cA*pwn, sv[256]=sum(cB*pwn) for the score
__global__ __launch_bounds__(1024) void k_bn_final(
    const double* __restrict__ psum, const double* __restrict__ psq,
    const float* __restrict__ gam, const float* __restrict__ bet,
    const float* __restrict__ pw, float* __restrict__ cA, float* __restrict__ cB,
    float* __restrict__ sv) {
  __shared__ double reds[4][256];
  __shared__ double redq[4][256];
  __shared__ double wsq[256];
  __shared__ double sb[256];
  const int t = threadIdx.x;
  const int c = t & 255, sl = t >> 8;
  double s = 0.0, q = 0.0;
  for (int i = sl * 64; i < sl * 64 + 64; i++) {
    s += psum[i * 256 + c];
    q += psq[i * 256 + c];
  }
  reds[sl][c] = s;
  redq[sl][c] = q;
  if (sl == 0) {
    double w = (double)pw[c];
    wsq[c] = w * w;
  }
  __syncthreads();
  if (t == 0) {
    double nn = 0.0;
    for (int i = 0; i < 256; i++) nn += wsq[i];
    wsq[0] = sqrt(nn);
  }
  __syncthreads();
  if (sl == 0) {
    s = reds[0][c] + reds[1][c] + reds[2][c] + reds[3][c];
    q = redq[0][c] + redq[1][c] + redq[2][c] + redq[3][c];
    double mean = s / (double)N_NODES;
    double var = q / (double)N_NODES - mean * mean;
    double a = (double)gam[c] / sqrt(var + 1e-5);
    double cb = (double)bet[c] - mean * a;
    cA[c] = (float)a;
    cB[c] = (float)cb;
    double pwnv = (double)pw[c] / wsq[0];
    sv[c] = (float)(a * pwnv);
    sb[c] = cb * pwnv;
  }
  __syncthreads();
  if (t == 0) {
    double s0 = 0.0;
    for (int i = 0; i < 256; i++) s0 += sb[i];
    sv[256] = (float)s0;
  }
}

// ---- score: one wave per node, coalesced ----
__global__ __launch_bounds__(256) void k_score(
    const float* __restrict__ feat, const float* __restrict__ sv,
    float* __restrict__ score) {
  const int lane = threadIdx.x & 63;
  const int node = blockIdx.x * 4 + (threadIdx.x >> 6);
  const int c0 = lane * 4;
  float4 f = *(const float4*)&feat[(size_t)node * 256 + c0];
  float4 w = *(const float4*)&sv[c0];
  float p = f.x * w.x + f.y * w.y + f.z * w.z + f.w * w.w;
#pragma unroll
  for (int d = 1; d < 64; d <<= 1) p += __shfl_xor(p, d, 64);
  if (lane == 0) score[node] = p + sv[256];
}

// ---- topk + gather: 8 blocks per graph, 64 nodes each ----
__global__ __launch_bounds__(256) void k_topk(
    const float* __restrict__ score, const float* __restrict__ feat,
    const float* __restrict__ cA, const float* __restrict__ cB,
    float* __restrict__ out) {
  __shared__ float ss[NPG];
  __shared__ int rnk[64];
  __shared__ float gt[64];
  const int g = blockIdx.x >> 3;
  const int part = blockIdx.x & 7;
  const int t = threadIdx.x;
  ss[t] = score[g * NPG + t];
  ss[t + 256] = score[g * NPG + t + 256];
  __syncthreads();
  const int ln = t & 3;
  const int ndl = part * 64 + (t >> 2);
  const float s = ss[ndl];
  int rank = 0;
  for (int j = ln * 128; j < ln * 128 + 128; j++) {
    float sj = ss[j];
    rank += (sj > s || (sj == s && j < ndl)) ? 1 : 0;
  }
  rank += __shfl_xor(rank, 1);
  rank += __shfl_xor(rank, 2);
  if (ln == 0) {
    rnk[t >> 2] = rank;
    gt[t >> 2] = tanhf(s);
  }
  __syncthreads();
  for (int idx = t; idx < 64 * 64; idx += 256) {
    int r = idx >> 6;
    int rank2 = rnk[r];
    if (rank2 < KKEEP) {
      int c4 = (idx & 63) * 4;
      int node = g * NPG + part * 64 + r;
      float4 f = *(const float4*)&feat[(size_t)node * 256 + c4];
      float4 a = *(const float4*)&cA[c4];
      float4 b = *(const float4*)&cB[c4];
      float tg = gt[r];
      float4 o;
      o.x = fmaf(f.x, a.x, b.x) * tg;
      o.y = fmaf(f.y, a.y, b.y) * tg;
      o.z = fmaf(f.z, a.z, b.z) * tg;
      o.w = fmaf(f.w, a.w, b.w) * tg;
      *(float4*)&out[(size_t)(g * KKEEP + rank2) * 256 + c4] = o;
    }
  }
}

extern "C" void kernel_launch(void* const* d_in, const int* in_sizes, int n_in,
                              void* d_out, int out_size, void* d_ws, size_t ws_size,
                              hipStream_t stream) {
  const float* x    = (const float*)d_in[0];
  const int*   ei   = (const int*)d_in[1];
  const float* W    = (const float*)d_in[2];
  const float* attS = (const float*)d_in[3];
  const float* attD = (const float*)d_in[4];
  const float* bias = (const float*)d_in[5];
  const float* gam  = (const float*)d_in[6];
  const float* bet  = (const float*)d_in[7];
  const float* pw   = (const float*)d_in[8];
  float* out = (float*)d_out;
  const int E = in_sizes[1] / 2;

  char* p = (char*)d_ws;
  float* h     = (float*)p; p += (size_t)N_NODES * 256 * 4;
  float* feat  = (float*)p; p += (size_t)N_NODES * 256 * 4;
  float* a_src = (float*)p; p += (size_t)N_NODES * 4 * 4;
  float* a_dst = (float*)p; p += (size_t)N_NODES * 4 * 4;
  float* score = (float*)p; p += (size_t)N_NODES * 4;
  double* psum = (double*)p; p += (size_t)256 * 256 * 8;
  double* psq  = (double*)p; p += (size_t)256 * 256 * 8;
  float* cA    = (float*)p; p += 256 * 4;
  float* cB    = (float*)p; p += 256 * 4;
  float* sv    = (float*)p; p += 260 * 4;
  unsigned short* wth  = (unsigned short*)p; p += (size_t)256 * 256 * 2;
  unsigned short* wtl  = (unsigned short*)p; p += (size_t)256 * 256 * 2;
  unsigned short* wtll = (unsigned short*)p; p += (size_t)256 * 256 * 2;
  int* cnt     = (int*)p;   p += (size_t)N_NODES * 4;
  unsigned short* nbr = (unsigned short*)p; p += (size_t)N_NODES * CAP * 2;

  hipMemsetAsync(cnt, 0, (size_t)N_NODES * 4, stream);
  k_conv<<<64, 256, 0, stream>>>(W, wth, wtl, wtll);
  k_gemm_hist<<<1536, 512, 0, stream>>>(x, wth, wtl, wtll, attS, attD,
                                        h, a_src, a_dst, ei, E, cnt, nbr);
  k_agg<<<N_NODES / 4, 256, 0, stream>>>(h, a_src, a_dst, cnt, nbr, bias, feat);
  k_bn_partial<<<256, 256, 0, stream>>>(feat, psum, psq);
  k_bn_final<<<1, 1024, 0, stream>>>(psum, psq, gam, bet, pw, cA, cB, sv);
  k_score<<<N_NODES / 4, 256, 0, stream>>>(feat, sv, score);
  k_topk<<<NGRAPH * 8, 256, 0, stream>>>(score, feat, cA, cB, out);
}

// Round 8
// 213.355 us; speedup vs baseline: 1.0343x; 1.0343x over previous
//
#include <hip/hip_runtime.h>
#include <math.h>

#define N_NODES 32768
#define NPG 512
#define NGRAPH 64
#define KKEEP 256
#define CAP 64

typedef __attribute__((ext_vector_type(8))) short short8;
typedef __attribute__((ext_vector_type(4))) float f32x4;

__device__ __forceinline__ unsigned short f2bf(float v) {
  unsigned u = __builtin_bit_cast(unsigned, v);
  u = (u + 0x7FFFu + ((u >> 16) & 1u)) >> 16;
  return (unsigned short)u;
}
__device__ __forceinline__ float bf2f(unsigned short u) {
  unsigned v = ((unsigned)u) << 16;
  return __builtin_bit_cast(float, v);
}

__device__ __forceinline__ void async_cp16(unsigned short* l, const unsigned short* g) {
  __builtin_amdgcn_global_load_lds(
      (const __attribute__((address_space(1))) unsigned int*)g,
      (__attribute__((address_space(3))) unsigned int*)l, 16, 0, 0);
}

// raw barrier: memory-clobber asm (blocks IR-level motion) + sched_barrier
// (blocks MIR-level motion, rule 18).  No implicit vmcnt(0) drain.
__device__ __forceinline__ void block_barrier() {
  __builtin_amdgcn_sched_barrier(0);
  asm volatile("s_barrier" ::: "memory");
  __builtin_amdgcn_sched_barrier(0);
}
__device__ __forceinline__ void wait_all() {
  asm volatile("s_waitcnt vmcnt(0) lgkmcnt(0)" ::: "memory");
  __builtin_amdgcn_sched_barrier(0);
}

// ---- W split-3 bf16 convert + cnt zeroing (blocks 64..95) ----
__global__ __launch_bounds__(256) void k_conv(
    const float* __restrict__ W,
    unsigned short* __restrict__ wth, unsigned short* __restrict__ wtl,
    unsigned short* __restrict__ wtll, int* __restrict__ cnt) {
  const int t = threadIdx.x;
  if (blockIdx.x >= 64) {
    int i = (blockIdx.x - 64) * 1024 + t * 4;
    *(int4*)&cnt[i] = make_int4(0, 0, 0, 0);
    return;
  }
  int n = blockIdx.x * 4 + (t >> 6);         // output col of W
  int k = (t & 63) * 4;
  unsigned short hb[4], lb[4], qb[4];
#pragma unroll
  for (int j = 0; j < 4; j++) {
    float v = W[(size_t)(k + j) * 256 + n];
    unsigned short hh = f2bf(v);
    float e1 = v - bf2f(hh);                 // exact
    unsigned short ll = f2bf(e1);
    float e2 = e1 - bf2f(ll);                // exact
    hb[j] = hh; lb[j] = ll; qb[j] = f2bf(e2);
  }
  *(uint2*)&wth[(size_t)n * 256 + k] = *(uint2*)&hb[0];
  *(uint2*)&wtl[(size_t)n * 256 + k] = *(uint2*)&lb[0];
  *(uint2*)&wtll[(size_t)n * 256 + k] = *(uint2*)&qb[0];
}

// ---- merged: pipelined MFMA split-3 GEMM (bid%3==0, 128x128, 512 thr)
//      + edge bucketing (bid%3!=0) INTERLEAVED so hist overlaps GEMM ----
// Round-6 GEMM body verbatim (best verified).  Interleaving removes the
// serialized hist tail: short hist blocks churn through CU slots while GEMM
// blocks run.  mb remapped so physical XCD (bid&7=(3g)&7) owns rows
// [4096*XCD, +4096) and nh-pairs (g, g+8) share an XCD -> k_agg locality kept.
// h / a_src / a_dst are bit-identical to the round-0 verified kernel.
#define A_STR 129
#define B_BASE 12384           // ushort
#define B_SZ 12288             // ushort: 3 planes x 4096
__global__ __launch_bounds__(512, 4) void k_gemm_hist(
    const float* __restrict__ x,
    const unsigned short* __restrict__ wth, const unsigned short* __restrict__ wtl,
    const unsigned short* __restrict__ wtll,
    const float* __restrict__ attS, const float* __restrict__ attD,
    float* __restrict__ h, float* __restrict__ a_src, float* __restrict__ a_dst,
    const int* __restrict__ ei, int E, int* __restrict__ cnt,
    unsigned short* __restrict__ nbr) {
  __shared__ unsigned short lds[36960];      // 73,920 B
  const int t = threadIdx.x;
  const int bid = blockIdx.x;
  if (bid % 3 != 0) {
    // edge bucketing: independent of GEMM, interleaved with it on the device
    int ord = bid - bid / 3 - 1;             // 0..1023
    int e = ord * 512 + t;
    if (e < E) {
      int s = ei[e];
      int d = ei[E + e];
      int slot = atomicAdd(&cnt[d], 1);
      if (slot < CAP) nbr[(size_t)d * CAP + slot] = (unsigned short)(s & (NPG - 1));
    }
    return;
  }
  const int g = bid / 3;                     // 0..511
  const int p = (3 * g) & 7;                 // physical XCD of this block
  const int mb = p * 32 + (g >> 4);          // XCD p owns rows [4096p, 4096p+4096)
  const int nh = (g >> 3) & 1;               // pair (g, g+8): same XCD, same mb
  const int row0 = mb * 128;
  const int wid = t >> 6, lane = t & 63;
  const int q = lane >> 4, ln = lane & 15;
  const int wm = (wid >> 1) * 32, wn = (wid & 1) * 64;
  const int sr = t >> 2, scq = t & 3;        // A staging: 128 rows x 4 k-octs
  f32x4 acc[2][4] = {};

  // ---- prologue: stage kc=0 ----
  {
    size_t ga = (size_t)(row0 + sr) * 256 + scq * 8;
    float4 f0 = *(const float4*)&x[ga];
    float4 f1 = *(const float4*)&x[ga + 4];
    float ff[8] = {f0.x, f0.y, f0.z, f0.w, f1.x, f1.y, f1.z, f1.w};
    unsigned short hs[8], ls[8], qs[8];
#pragma unroll
    for (int j = 0; j < 8; j++) {
      unsigned short hh = f2bf(ff[j]);
      float e1 = ff[j] - bf2f(hh);
      unsigned short ll = f2bf(e1);
      float e2 = e1 - bf2f(ll);
      hs[j] = hh; ls[j] = ll; qs[j] = f2bf(e2);
    }
    *(uint4*)&lds[((0 * 4 + scq) * A_STR + sr) * 8] = *(uint4*)&hs[0];
    *(uint4*)&lds[((1 * 4 + scq) * A_STR + sr) * 8] = *(uint4*)&ls[0];
    *(uint4*)&lds[((2 * 4 + scq) * A_STR + sr) * 8] = *(uint4*)&qs[0];
    size_t gb = (size_t)(nh * 128 + (t & 127)) * 256 + (t >> 7) * 8;
    async_cp16(&lds[B_BASE + 0 * 4096 + t * 8], &wth[gb]);
    async_cp16(&lds[B_BASE + 1 * 4096 + t * 8], &wtl[gb]);
    async_cp16(&lds[B_BASE + 2 * 4096 + t * 8], &wtll[gb]);
  }
  wait_all();
  block_barrier();

  for (int kc = 0; kc < 8; kc++) {
    const int cur = kc & 1;
    // issue next-tile loads FIRST (in flight across the whole MFMA phase)
    float4 f0, f1;
    if (kc < 7) {
      const int k1 = (kc + 1) * 32;
      size_t ga = (size_t)(row0 + sr) * 256 + k1 + scq * 8;
      f0 = *(const float4*)&x[ga];
      f1 = *(const float4*)&x[ga + 4];
      unsigned short* bb = &lds[B_BASE + (cur ^ 1) * B_SZ];
      size_t gb = (size_t)(nh * 128 + (t & 127)) * 256 + k1 + (t >> 7) * 8;
      async_cp16(&bb[0 * 4096 + t * 8], &wth[gb]);
      async_cp16(&bb[1 * 4096 + t * 8], &wtl[gb]);
      async_cp16(&bb[2 * 4096 + t * 8], &wtll[gb]);
    }
    // compute on buf[cur]
    const unsigned short* bc = &lds[B_BASE + cur * B_SZ];
    short8 ah[2], al[2], aq[2];
#pragma unroll
    for (int mt = 0; mt < 2; mt++) {
      int r = wm + mt * 16 + ln;
      ah[mt] = *(const short8*)&lds[((0 * 4 + q) * A_STR + r) * 8];
      al[mt] = *(const short8*)&lds[((1 * 4 + q) * A_STR + r) * 8];
      aq[mt] = *(const short8*)&lds[((2 * 4 + q) * A_STR + r) * 8];
    }
#pragma unroll
    for (int nt = 0; nt < 4; nt++) {
      int r = wn + nt * 16 + ln;
      short8 bh = *(const short8*)&bc[0 * 4096 + (q * 128 + r) * 8];
      short8 bl = *(const short8*)&bc[1 * 4096 + (q * 128 + r) * 8];
      short8 bq = *(const short8*)&bc[2 * 4096 + (q * 128 + r) * 8];
#pragma unroll
      for (int mt = 0; mt < 2; mt++) {
        acc[mt][nt] = __builtin_amdgcn_mfma_f32_16x16x32_bf16(ah[mt], bh, acc[mt][nt], 0, 0, 0);
        acc[mt][nt] = __builtin_amdgcn_mfma_f32_16x16x32_bf16(ah[mt], bl, acc[mt][nt], 0, 0, 0);
        acc[mt][nt] = __builtin_amdgcn_mfma_f32_16x16x32_bf16(al[mt], bh, acc[mt][nt], 0, 0, 0);
        acc[mt][nt] = __builtin_amdgcn_mfma_f32_16x16x32_bf16(ah[mt], bq, acc[mt][nt], 0, 0, 0);
        acc[mt][nt] = __builtin_amdgcn_mfma_f32_16x16x32_bf16(al[mt], bl, acc[mt][nt], 0, 0, 0);
        acc[mt][nt] = __builtin_amdgcn_mfma_f32_16x16x32_bf16(aq[mt], bh, acc[mt][nt], 0, 0, 0);
      }
    }
    // convert next A while B(kc+1) is still in flight
    unsigned short hs[8], ls[8], qs[8];
    if (kc < 7) {
      float ff[8] = {f0.x, f0.y, f0.z, f0.w, f1.x, f1.y, f1.z, f1.w};
#pragma unroll
      for (int j = 0; j < 8; j++) {
        unsigned short hh = f2bf(ff[j]);
        float e1 = ff[j] - bf2f(hh);
        unsigned short ll = f2bf(e1);
        float e2 = e1 - bf2f(ll);
        hs[j] = hh; ls[j] = ll; qs[j] = f2bf(e2);
      }
    }
    block_barrier();            // all waves done READING the A buffer
    if (kc < 7) {
      *(uint4*)&lds[((0 * 4 + scq) * A_STR + sr) * 8] = *(uint4*)&hs[0];
      *(uint4*)&lds[((1 * 4 + scq) * A_STR + sr) * 8] = *(uint4*)&ls[0];
      *(uint4*)&lds[((2 * 4 + scq) * A_STR + sr) * 8] = *(uint4*)&qs[0];
    }
    wait_all();                 // A writes visible; B(kc+1) landed (issued early)
    block_barrier();
  }

  // epilogue: store h; att partials via LDS transpose (aliased over staging).
  // XOR swizzle (ln^(q*4)) is bijective per row; read back in ln order ->
  // bit-identical sums to the round-0 epilogue.
  const int head = nh * 2 + (wid & 1);
  float sA[4], sD[4];
#pragma unroll
  for (int nt = 0; nt < 4; nt++) {
    int n = nh * 128 + wn + nt * 16 + ln;
    sA[nt] = attS[n];
    sD[nt] = attD[n];
  }
  float2* epi = (float2*)lds;   // [wid(8)][q(4)][row(8)][18] float2
#pragma unroll
  for (int mt = 0; mt < 2; mt++) {
#pragma unroll
    for (int reg = 0; reg < 4; reg++) {
      int m = row0 + wm + mt * 16 + q * 4 + reg;
      float ps = 0.f, pd = 0.f;
#pragma unroll
      for (int nt = 0; nt < 4; nt++) {
        float v = acc[mt][nt][reg];
        h[(size_t)m * 256 + nh * 128 + wn + nt * 16 + ln] = v;
        ps = fmaf(v, sA[nt], ps);
        pd = fmaf(v, sD[nt], pd);
      }
      epi[(((wid * 4 + q) * 8) + mt * 4 + reg) * 18 + (ln ^ (q * 4))] =
          make_float2(ps, pd);
    }
  }
  __syncthreads();
  if (lane < 32) {
    const int rr2 = lane & 7;                // mt*4+reg
    const int q2 = lane >> 3;                // row group's q
    const int base = (((wid * 4 + q2) * 8) + rr2) * 18;
    float ps = 0.f, pd = 0.f;
#pragma unroll
    for (int i = 0; i < 16; i++) {
      float2 v = epi[base + (i ^ (q2 * 4))];
      ps += v.x;
      pd += v.y;
    }
    int m = row0 + wm + (rr2 >> 2) * 16 + q2 * 4 + (rr2 & 3);
    a_src[m * 4 + head] = ps;
    a_dst[m * 4 + head] = pd;
  }
}

// ---- aggregation: softmax weights computed once, broadcast via LDS ----
__global__ __launch_bounds__(256) void k_agg(
    const float* __restrict__ h, const float* __restrict__ a_src,
    const float* __restrict__ a_dst, const int* __restrict__ cnt,
    const unsigned short* __restrict__ nbr, const float* __restrict__ bias,
    float* __restrict__ feat) {
  __shared__ float p_lds[4][68][4];
  __shared__ int s_lds[4][68];
  const int wv = threadIdx.x >> 6;
  const int lane = threadIdx.x & 63;
  int nb = (blockIdx.x & 7) * (N_NODES / 4 / 8) + (blockIdx.x >> 3);
  const int node = nb * 4 + wv;
  const int head = lane >> 4;
  const int li = lane & 15;
  const int c0 = lane * 4;
  const int base = node & ~(NPG - 1);
  const float ad = a_dst[node * 4 + head];
  int n = cnt[node];
  if (n > CAP) n = CAP;
  float e_reg[5];
  int srcs[5];
  int nit = 0;
  float m = -1e30f;
  for (int j = li; j <= n; j += 16) {
    int s = (j < n) ? base + (int)nbr[(size_t)node * CAP + j] : node;
    float e = a_src[s * 4 + head] + ad;
    e = (e > 0.f) ? e : 0.2f * e;
    srcs[nit] = s;
    e_reg[nit++] = e;
    m = fmaxf(m, e);
  }
#pragma unroll
  for (int d = 1; d < 16; d <<= 1) m = fmaxf(m, __shfl_xor(m, d, 16));
  float l = 0.f;
  for (int i = 0; i < nit; i++) {
    int j = li + i * 16;
    float p = __expf(e_reg[i] - m);
    l += p;
    p_lds[wv][j][head] = p;
    if (head == 0) s_lds[wv][j] = srcs[i];
  }
#pragma unroll
  for (int d = 1; d < 16; d <<= 1) l += __shfl_xor(l, d, 16);
  const float linv = 1.f / (l + 1e-16f);
  __builtin_amdgcn_s_waitcnt(0);
  float4 acc0 = make_float4(0.f, 0.f, 0.f, 0.f);
  float4 acc1 = make_float4(0.f, 0.f, 0.f, 0.f);
  int j = 0;
  for (; j + 1 <= n; j += 2) {
    float p0 = p_lds[wv][j][head];
    float p1 = p_lds[wv][j + 1][head];
    int s0 = s_lds[wv][j];
    int s1 = s_lds[wv][j + 1];
    float4 h0 = *(const float4*)&h[(size_t)s0 * 256 + c0];
    float4 h1 = *(const float4*)&h[(size_t)s1 * 256 + c0];
    acc0.x = fmaf(p0, h0.x, acc0.x); acc1.x = fmaf(p1, h1.x, acc1.x);
    acc0.y = fmaf(p0, h0.y, acc0.y); acc1.y = fmaf(p1, h1.y, acc1.y);
    acc0.z = fmaf(p0, h0.z, acc0.z); acc1.z = fmaf(p1, h1.z, acc1.z);
    acc0.w = fmaf(p0, h0.w, acc0.w); acc1.w = fmaf(p1, h1.w, acc1.w);
  }
  if (j <= n) {
    float p0 = p_lds[wv][j][head];
    int s0 = s_lds[wv][j];
    float4 h0 = *(const float4*)&h[(size_t)s0 * 256 + c0];
    acc0.x = fmaf(p0, h0.x, acc0.x);
    acc0.y = fmaf(p0, h0.y, acc0.y);
    acc0.z = fmaf(p0, h0.z, acc0.z);
    acc0.w = fmaf(p0, h0.w, acc0.w);
  }
  const float4 b4 = *(const float4*)&bias[c0];
  float4 o;
  o.x = fmaxf(fmaf(acc0.x + acc1.x, linv, b4.x), 0.f);
  o.y = fmaxf(fmaf(acc0.y + acc1.y, linv, b4.y), 0.f);
  o.z = fmaxf(fmaf(acc0.z + acc1.z, linv, b4.z), 0.f);
  o.w = fmaxf(fmaf(acc0.w + acc1.w, linv, b4.w), 0.f);
  *(float4*)&feat[(size_t)node * 256 + c0] = o;
}

// ---- BN stats: 1024 blocks x 64 thr (chunk x 4 col-groups).  Each column
// still summed by ONE thread over the same 128 rows in the same order ->
// bit-identical psum/psq; 4x resident waves hide the f64 chain latency. ----
__global__ __launch_bounds__(64) void k_bn_partial(const float* __restrict__ feat,
                                                   double* __restrict__ psum,
                                                   double* __restrict__ psq) {
  const int chunk = blockIdx.x >> 2;
  const int c = (blockIdx.x & 3) * 64 + threadIdx.x;
  const int r0 = chunk * 128;
  double s = 0.0, q = 0.0;
  for (int i = 0; i < 128; i++) {
    double v = (double)feat[(size_t)(r0 + i) * 256 + c];
    s += v;
    q += v * v;
  }
  psum[chunk * 256 + c] = s;
  psq[chunk * 256 + c] = q;
}

// cA/cB for output BN; sv[c]=cA*pwn, sv[256]=sum(cB*pwn) for the score
__global__ __launch_bounds__(1024) void k_bn_final(
    const double* __restrict__ psum, const double* __restrict__ psq,
    const float* __restrict__ gam, const float* __restrict__ bet,
    const float* __restrict__ pw, float* __restrict__ cA, float* __restrict__ cB,
    float* __restrict__ sv) {
  __shared__ double reds[4][256];
  __shared__ double redq[4][256];
  __shared__ double wsq[256];
  __shared__ double sb[256];
  const int t = threadIdx.x;
  const int c = t & 255, sl = t >> 8;
  double s = 0.0, q = 0.0;
  for (int i = sl * 64; i < sl * 64 + 64; i++) {
    s += psum[i * 256 + c];
    q += psq[i * 256 + c];
  }
  reds[sl][c] = s;
  redq[sl][c] = q;
  if (sl == 0) {
    double w = (double)pw[c];
    wsq[c] = w * w;
  }
  __syncthreads();
  if (t == 0) {
    double nn = 0.0;
    for (int i = 0; i < 256; i++) nn += wsq[i];
    wsq[0] = sqrt(nn);
  }
  __syncthreads();
  if (sl == 0) {
    s = reds[0][c] + reds[1][c] + reds[2][c] + reds[3][c];
    q = redq[0][c] + redq[1][c] + redq[2][c] + redq[3][c];
    double mean = s / (double)N_NODES;
    double var = q / (double)N_NODES - mean * mean;
    double a = (double)gam[c] / sqrt(var + 1e-5);
    double cb = (double)bet[c] - mean * a;
    cA[c] = (float)a;
    cB[c] = (float)cb;
    double pwnv = (double)pw[c] / wsq[0];
    sv[c] = (float)(a * pwnv);
    sb[c] = cb * pwnv;
  }
  __syncthreads();
  if (t == 0) {
    double s0 = 0.0;
    for (int i = 0; i < 256; i++) s0 += sb[i];
    sv[256] = (float)s0;
  }
}

// ---- score: one wave per node, coalesced ----
__global__ __launch_bounds__(256) void k_score(
    const float* __restrict__ feat, const float* __restrict__ sv,
    float* __restrict__ score) {
  const int lane = threadIdx.x & 63;
  const int node = blockIdx.x * 4 + (threadIdx.x >> 6);
  const int c0 = lane * 4;
  float4 f = *(const float4*)&feat[(size_t)node * 256 + c0];
  float4 w = *(const float4*)&sv[c0];
  float p = f.x * w.x + f.y * w.y + f.z * w.z + f.w * w.w;
#pragma unroll
  for (int d = 1; d < 64; d <<= 1) p += __shfl_xor(p, d, 64);
  if (lane == 0) score[node] = p + sv[256];
}

// ---- topk + gather: 8 blocks per graph, 64 nodes each ----
__global__ __launch_bounds__(256) void k_topk(
    const float* __restrict__ score, const float* __restrict__ feat,
    const float* __restrict__ cA, const float* __restrict__ cB,
    float* __restrict__ out) {
  __shared__ float ss[NPG];
  __shared__ int rnk[64];
  __shared__ float gt[64];
  const int g = blockIdx.x >> 3;
  const int part = blockIdx.x & 7;
  const int t = threadIdx.x;
  ss[t] = score[g * NPG + t];
  ss[t + 256] = score[g * NPG + t + 256];
  __syncthreads();
  const int ln = t & 3;
  const int ndl = part * 64 + (t >> 2);
  const float s = ss[ndl];
  int rank = 0;
  for (int j = ln * 128; j < ln * 128 + 128; j++) {
    float sj = ss[j];
    rank += (sj > s || (sj == s && j < ndl)) ? 1 : 0;
  }
  rank += __shfl_xor(rank, 1);
  rank += __shfl_xor(rank, 2);
  if (ln == 0) {
    rnk[t >> 2] = rank;
    gt[t >> 2] = tanhf(s);
  }
  __syncthreads();
  for (int idx = t; idx < 64 * 64; idx += 256) {
    int r = idx >> 6;
    int rank2 = rnk[r];
    if (rank2 < KKEEP) {
      int c4 = (idx & 63) * 4;
      int node = g * NPG + part * 64 + r;
      float4 f = *(const float4*)&feat[(size_t)node * 256 + c4];
      float4 a = *(const float4*)&cA[c4];
      float4 b = *(const float4*)&cB[c4];
      float tg = gt[r];
      float4 o;
      o.x = fmaf(f.x, a.x, b.x) * tg;
      o.y = fmaf(f.y, a.y, b.y) * tg;
      o.z = fmaf(f.z, a.z, b.z) * tg;
      o.w = fmaf(f.w, a.w, b.w) * tg;
      *(float4*)&out[(size_t)(g * KKEEP + rank2) * 256 + c4] = o;
    }
  }
}

extern "C" void kernel_launch(void* const* d_in, const int* in_sizes, int n_in,
                              void* d_out, int out_size, void* d_ws, size_t ws_size,
                              hipStream_t stream) {
  const float* x    = (const float*)d_in[0];
  const int*   ei   = (const int*)d_in[1];
  const float* W    = (const float*)d_in[2];
  const float* attS = (const float*)d_in[3];
  const float* attD = (const float*)d_in[4];
  const float* bias = (const float*)d_in[5];
  const float* gam  = (const float*)d_in[6];
  const float* bet  = (const float*)d_in[7];
  const float* pw   = (const float*)d_in[8];
  float* out = (float*)d_out;
  const int E = in_sizes[1] / 2;

  char* p = (char*)d_ws;
  float* h     = (float*)p; p += (size_t)N_NODES * 256 * 4;
  float* feat  = (float*)p; p += (size_t)N_NODES * 256 * 4;
  float* a_src = (float*)p; p += (size_t)N_NODES * 4 * 4;
  float* a_dst = (float*)p; p += (size_t)N_NODES * 4 * 4;
  float* score = (float*)p; p += (size_t)N_NODES * 4;
  double* psum = (double*)p; p += (size_t)256 * 256 * 8;
  double* psq  = (double*)p; p += (size_t)256 * 256 * 8;
  float* cA    = (float*)p; p += 256 * 4;
  float* cB    = (float*)p; p += 256 * 4;
  float* sv    = (float*)p; p += 260 * 4;
  unsigned short* wth  = (unsigned short*)p; p += (size_t)256 * 256 * 2;
  unsigned short* wtl  = (unsigned short*)p; p += (size_t)256 * 256 * 2;
  unsigned short* wtll = (unsigned short*)p; p += (size_t)256 * 256 * 2;
  int* cnt     = (int*)p;   p += (size_t)N_NODES * 4;
  unsigned short* nbr = (unsigned short*)p; p += (size_t)N_NODES * CAP * 2;

  k_conv<<<96, 256, 0, stream>>>(W, wth, wtl, wtll, cnt);
  k_gemm_hist<<<1536, 512, 0, stream>>>(x, wth, wtl, wtll, attS, attD,
                                        h, a_src, a_dst, ei, E, cnt, nbr);
  k_agg<<<N_NODES / 4, 256, 0, stream>>>(h, a_src, a_dst, cnt, nbr, bias, feat);
  k_bn_partial<<<1024, 64, 0, stream>>>(feat, psum, psq);
  k_bn_final<<<1, 1024, 0, stream>>>(psum, psq, gam, bet, pw, cA, cB, sv);
  k_score<<<N_NODES / 4, 256, 0, stream>>>(feat, sv, score);
  k_topk<<<NGRAPH * 8, 256, 0, stream>>>(score, feat, cA, cB, out);
}

// Round 9
// 205.997 us; speedup vs baseline: 1.0713x; 1.0357x over previous
//
#include <hip/hip_runtime.h>
#include <math.h>

#define N_NODES 32768
#define NPG 512
#define NGRAPH 64
#define KKEEP 256
#define CAP 64

typedef __attribute__((ext_vector_type(8))) short short8;
typedef __attribute__((ext_vector_type(4))) float f32x4;

__device__ __forceinline__ unsigned short f2bf(float v) {
  unsigned u = __builtin_bit_cast(unsigned, v);
  u = (u + 0x7FFFu + ((u >> 16) & 1u)) >> 16;
  return (unsigned short)u;
}
__device__ __forceinline__ float bf2f(unsigned short u) {
  unsigned v = ((unsigned)u) << 16;
  return __builtin_bit_cast(float, v);
}

__device__ __forceinline__ void async_cp16(unsigned short* l, const unsigned short* g) {
  __builtin_amdgcn_global_load_lds(
      (const __attribute__((address_space(1))) unsigned int*)g,
      (__attribute__((address_space(3))) unsigned int*)l, 16, 0, 0);
}

// raw barrier: memory-clobber asm (blocks IR-level motion) + sched_barrier
// (blocks MIR-level motion, rule 18).  No implicit vmcnt(0) drain.
__device__ __forceinline__ void block_barrier() {
  __builtin_amdgcn_sched_barrier(0);
  asm volatile("s_barrier" ::: "memory");
  __builtin_amdgcn_sched_barrier(0);
}
__device__ __forceinline__ void wait_all() {
  asm volatile("s_waitcnt vmcnt(0) lgkmcnt(0)" ::: "memory");
  __builtin_amdgcn_sched_barrier(0);
}

// ---- W split-3 bf16 convert + cnt zeroing (blocks 64..95) ----
__global__ __launch_bounds__(256) void k_conv(
    const float* __restrict__ W,
    unsigned short* __restrict__ wth, unsigned short* __restrict__ wtl,
    unsigned short* __restrict__ wtll, int* __restrict__ cnt) {
  const int t = threadIdx.x;
  if (blockIdx.x >= 64) {
    int i = (blockIdx.x - 64) * 1024 + t * 4;
    *(int4*)&cnt[i] = make_int4(0, 0, 0, 0);
    return;
  }
  int n = blockIdx.x * 4 + (t >> 6);         // output col of W
  int k = (t & 63) * 4;
  unsigned short hb[4], lb[4], qb[4];
#pragma unroll
  for (int j = 0; j < 4; j++) {
    float v = W[(size_t)(k + j) * 256 + n];
    unsigned short hh = f2bf(v);
    float e1 = v - bf2f(hh);                 // exact
    unsigned short ll = f2bf(e1);
    float e2 = e1 - bf2f(ll);                // exact
    hb[j] = hh; lb[j] = ll; qb[j] = f2bf(e2);
  }
  *(uint2*)&wth[(size_t)n * 256 + k] = *(uint2*)&hb[0];
  *(uint2*)&wtl[(size_t)n * 256 + k] = *(uint2*)&lb[0];
  *(uint2*)&wtll[(size_t)n * 256 + k] = *(uint2*)&qb[0];
}

// ---- merged: MFMA split-3 GEMM (blocks 0..511, 128x128, 256 thr, acc[4][4])
//      + edge bucketing tail (blocks 512..2559) ----
// Compute structure = round-0 verified (4 waves, 96 MFMA/wave/kc: best LDS
// traffic per FLOP).  Staging = round-6 verified schedule: B double-buffered
// via global_load_lds issued at TOP of iteration; A single-buffered (x loads
// early, convert after MFMA, ds_write between raw barriers), A_STR=129 pad.
// h / a_src / a_dst are bit-identical to the round-0 verified kernel.
#define A_STR 129
#define B_BASE 12384           // ushort; A occupies < 12384
#define B_SZ 12288             // ushort: 3 planes x 4096
__global__ __launch_bounds__(256, 2) void k_gemm_hist(
    const float* __restrict__ x,
    const unsigned short* __restrict__ wth, const unsigned short* __restrict__ wtl,
    const unsigned short* __restrict__ wtll,
    const float* __restrict__ attS, const float* __restrict__ attD,
    float* __restrict__ h, float* __restrict__ a_src, float* __restrict__ a_dst,
    const int* __restrict__ ei, int E, int* __restrict__ cnt,
    unsigned short* __restrict__ nbr) {
  __shared__ unsigned short lds[36960];      // 73,920 B -> 2 blocks/CU
  const int t = threadIdx.x;
  const int bid = blockIdx.x;
  if (bid >= 512) {
    // edge bucketing: independent of GEMM, backfills behind it (r4 pattern)
    int e = (bid - 512) * 256 + t;
    if (e < E) {
      int s = ei[e];
      int d = ei[E + e];
      int slot = atomicAdd(&cnt[d], 1);
      if (slot < CAP) nbr[(size_t)d * CAP + slot] = (unsigned short)(s & (NPG - 1));
    }
    return;
  }
  // XCD pairing: both nh halves of an mb land on the same XCD (bid%8);
  // XCD c owns mb in [32c, 32c+32) -> A rows [4096c, 4096c+4096), matches k_agg.
  const int mb = (bid & 7) * 32 + (bid >> 4);
  const int nh = (bid >> 3) & 1;
  const int row0 = mb * 128;
  const int wid = t >> 6, lane = t & 63;
  const int q = lane >> 4, ln = lane & 15;
  const int wm = (wid >> 1) * 64, wn = (wid & 1) * 64;
  f32x4 acc[4][4] = {};

  // ---- prologue: stage A(0) + B(0) ----
#pragma unroll
  for (int i = 0; i < 2; i++) {
    int c = i * 256 + t;
    int r = c >> 2, cq = c & 3;
    size_t ga = (size_t)(row0 + r) * 256 + cq * 8;
    float4 f0 = *(const float4*)&x[ga];
    float4 f1 = *(const float4*)&x[ga + 4];
    float ff[8] = {f0.x, f0.y, f0.z, f0.w, f1.x, f1.y, f1.z, f1.w};
    unsigned short hs[8], ls[8], qs[8];
#pragma unroll
    for (int j = 0; j < 8; j++) {
      unsigned short hh = f2bf(ff[j]);
      float e1 = ff[j] - bf2f(hh);
      unsigned short ll = f2bf(e1);
      float e2 = e1 - bf2f(ll);
      hs[j] = hh; ls[j] = ll; qs[j] = f2bf(e2);
    }
    *(uint4*)&lds[((0 * 4 + cq) * A_STR + r) * 8] = *(uint4*)&hs[0];
    *(uint4*)&lds[((1 * 4 + cq) * A_STR + r) * 8] = *(uint4*)&ls[0];
    *(uint4*)&lds[((2 * 4 + cq) * A_STR + r) * 8] = *(uint4*)&qs[0];
    size_t gb = (size_t)(nh * 128 + (c & 127)) * 256 + (c >> 7) * 8;
    async_cp16(&lds[B_BASE + 0 * 4096 + c * 8], &wth[gb]);
    async_cp16(&lds[B_BASE + 1 * 4096 + c * 8], &wtl[gb]);
    async_cp16(&lds[B_BASE + 2 * 4096 + c * 8], &wtll[gb]);
  }
  wait_all();
  block_barrier();

  for (int kc = 0; kc < 8; kc++) {
    const int cur = kc & 1;
    // issue next-tile loads FIRST (in flight across the whole MFMA phase)
    float4 nf[4];
    if (kc < 7) {
      const int k1 = (kc + 1) * 32;
      unsigned short* bb = &lds[B_BASE + (cur ^ 1) * B_SZ];
#pragma unroll
      for (int i = 0; i < 2; i++) {
        int c = i * 256 + t;
        int r = c >> 2, cq = c & 3;
        size_t ga = (size_t)(row0 + r) * 256 + k1 + cq * 8;
        nf[i * 2 + 0] = *(const float4*)&x[ga];
        nf[i * 2 + 1] = *(const float4*)&x[ga + 4];
        size_t gb = (size_t)(nh * 128 + (c & 127)) * 256 + k1 + (c >> 7) * 8;
        async_cp16(&bb[0 * 4096 + c * 8], &wth[gb]);
        async_cp16(&bb[1 * 4096 + c * 8], &wtl[gb]);
        async_cp16(&bb[2 * 4096 + c * 8], &wtll[gb]);
      }
    }
    // compute on A + B[cur]  (round-0 exact MFMA order)
    const unsigned short* bc = &lds[B_BASE + cur * B_SZ];
    short8 ah[4], al[4], aq[4];
#pragma unroll
    for (int mt = 0; mt < 4; mt++) {
      int r = wm + mt * 16 + ln;
      ah[mt] = *(const short8*)&lds[((0 * 4 + q) * A_STR + r) * 8];
      al[mt] = *(const short8*)&lds[((1 * 4 + q) * A_STR + r) * 8];
      aq[mt] = *(const short8*)&lds[((2 * 4 + q) * A_STR + r) * 8];
    }
#pragma unroll
    for (int nt = 0; nt < 4; nt++) {
      int r = wn + nt * 16 + ln;
      short8 bh = *(const short8*)&bc[0 * 4096 + (q * 128 + r) * 8];
      short8 bl = *(const short8*)&bc[1 * 4096 + (q * 128 + r) * 8];
      short8 bq = *(const short8*)&bc[2 * 4096 + (q * 128 + r) * 8];
#pragma unroll
      for (int mt = 0; mt < 4; mt++) {
        acc[mt][nt] = __builtin_amdgcn_mfma_f32_16x16x32_bf16(ah[mt], bh, acc[mt][nt], 0, 0, 0);
        acc[mt][nt] = __builtin_amdgcn_mfma_f32_16x16x32_bf16(ah[mt], bl, acc[mt][nt], 0, 0, 0);
        acc[mt][nt] = __builtin_amdgcn_mfma_f32_16x16x32_bf16(al[mt], bh, acc[mt][nt], 0, 0, 0);
        acc[mt][nt] = __builtin_amdgcn_mfma_f32_16x16x32_bf16(ah[mt], bq, acc[mt][nt], 0, 0, 0);
        acc[mt][nt] = __builtin_amdgcn_mfma_f32_16x16x32_bf16(al[mt], bl, acc[mt][nt], 0, 0, 0);
        acc[mt][nt] = __builtin_amdgcn_mfma_f32_16x16x32_bf16(aq[mt], bh, acc[mt][nt], 0, 0, 0);
      }
    }
    // convert next A while B(kc+1) is still in flight
    unsigned short hs[2][8], ls[2][8], qs[2][8];
    if (kc < 7) {
#pragma unroll
      for (int i = 0; i < 2; i++) {
        float ff[8] = {nf[i * 2].x, nf[i * 2].y, nf[i * 2].z, nf[i * 2].w,
                       nf[i * 2 + 1].x, nf[i * 2 + 1].y, nf[i * 2 + 1].z, nf[i * 2 + 1].w};
#pragma unroll
        for (int j = 0; j < 8; j++) {
          unsigned short hh = f2bf(ff[j]);
          float e1 = ff[j] - bf2f(hh);
          unsigned short ll = f2bf(e1);
          float e2 = e1 - bf2f(ll);
          hs[i][j] = hh; ls[i][j] = ll; qs[i][j] = f2bf(e2);
        }
      }
    }
    block_barrier();            // all waves done READING the A buffer
    if (kc < 7) {
#pragma unroll
      for (int i = 0; i < 2; i++) {
        int c = i * 256 + t;
        int r = c >> 2, cq = c & 3;
        *(uint4*)&lds[((0 * 4 + cq) * A_STR + r) * 8] = *(uint4*)&hs[i][0];
        *(uint4*)&lds[((1 * 4 + cq) * A_STR + r) * 8] = *(uint4*)&ls[i][0];
        *(uint4*)&lds[((2 * 4 + cq) * A_STR + r) * 8] = *(uint4*)&qs[i][0];
      }
    }
    wait_all();                 // A writes visible; B(kc+1) landed (issued early)
    block_barrier();
  }

  // epilogue: store h; att partials via LDS transpose (aliased over staging).
  // XOR swizzle (ln^(q*4)) is bijective per row; read back in ln order ->
  // bit-identical sums to the round-0 epilogue.
  const int head = nh * 2 + (wid & 1);
  float sA[4], sD[4];
#pragma unroll
  for (int nt = 0; nt < 4; nt++) {
    int n = nh * 128 + wn + nt * 16 + ln;
    sA[nt] = attS[n];
    sD[nt] = attD[n];
  }
  float2* epi = (float2*)lds;   // [wid(4)][q(4)][row(16)][18] float2
#pragma unroll
  for (int mt = 0; mt < 4; mt++) {
#pragma unroll
    for (int reg = 0; reg < 4; reg++) {
      int m = row0 + wm + mt * 16 + q * 4 + reg;
      float ps = 0.f, pd = 0.f;
#pragma unroll
      for (int nt = 0; nt < 4; nt++) {
        float v = acc[mt][nt][reg];
        h[(size_t)m * 256 + nh * 128 + wn + nt * 16 + ln] = v;
        ps = fmaf(v, sA[nt], ps);
        pd = fmaf(v, sD[nt], pd);
      }
      epi[(((wid * 4 + q) * 16) + mt * 4 + reg) * 18 + (ln ^ (q * 4))] =
          make_float2(ps, pd);
    }
  }
  __syncthreads();
  {
    const int q2 = lane >> 4, rr = lane & 15;
    const int base = (((wid * 4 + q2) * 16) + rr) * 18;
    float ps = 0.f, pd = 0.f;
#pragma unroll
    for (int i = 0; i < 16; i++) {
      float2 v = epi[base + (i ^ (q2 * 4))];
      ps += v.x;
      pd += v.y;
    }
    int m = row0 + wm + (rr >> 2) * 16 + q2 * 4 + (rr & 3);
    a_src[m * 4 + head] = ps;
    a_dst[m * 4 + head] = pd;
  }
}

// ---- aggregation: softmax weights computed once, broadcast via LDS ----
__global__ __launch_bounds__(256) void k_agg(
    const float* __restrict__ h, const float* __restrict__ a_src,
    const float* __restrict__ a_dst, const int* __restrict__ cnt,
    const unsigned short* __restrict__ nbr, const float* __restrict__ bias,
    float* __restrict__ feat) {
  __shared__ float p_lds[4][68][4];
  __shared__ int s_lds[4][68];
  const int wv = threadIdx.x >> 6;
  const int lane = threadIdx.x & 63;
  int nb = (blockIdx.x & 7) * (N_NODES / 4 / 8) + (blockIdx.x >> 3);
  const int node = nb * 4 + wv;
  const int head = lane >> 4;
  const int li = lane & 15;
  const int c0 = lane * 4;
  const int base = node & ~(NPG - 1);
  const float ad = a_dst[node * 4 + head];
  int n = cnt[node];
  if (n > CAP) n = CAP;
  float e_reg[5];
  int srcs[5];
  int nit = 0;
  float m = -1e30f;
  for (int j = li; j <= n; j += 16) {
    int s = (j < n) ? base + (int)nbr[(size_t)node * CAP + j] : node;
    float e = a_src[s * 4 + head] + ad;
    e = (e > 0.f) ? e : 0.2f * e;
    srcs[nit] = s;
    e_reg[nit++] = e;
    m = fmaxf(m, e);
  }
#pragma unroll
  for (int d = 1; d < 16; d <<= 1) m = fmaxf(m, __shfl_xor(m, d, 16));
  float l = 0.f;
  for (int i = 0; i < nit; i++) {
    int j = li + i * 16;
    float p = __expf(e_reg[i] - m);
    l += p;
    p_lds[wv][j][head] = p;
    if (head == 0) s_lds[wv][j] = srcs[i];
  }
#pragma unroll
  for (int d = 1; d < 16; d <<= 1) l += __shfl_xor(l, d, 16);
  const float linv = 1.f / (l + 1e-16f);
  __builtin_amdgcn_s_waitcnt(0);
  float4 acc0 = make_float4(0.f, 0.f, 0.f, 0.f);
  float4 acc1 = make_float4(0.f, 0.f, 0.f, 0.f);
  int j = 0;
  for (; j + 1 <= n; j += 2) {
    float p0 = p_lds[wv][j][head];
    float p1 = p_lds[wv][j + 1][head];
    int s0 = s_lds[wv][j];
    int s1 = s_lds[wv][j + 1];
    float4 h0 = *(const float4*)&h[(size_t)s0 * 256 + c0];
    float4 h1 = *(const float4*)&h[(size_t)s1 * 256 + c0];
    acc0.x = fmaf(p0, h0.x, acc0.x); acc1.x = fmaf(p1, h1.x, acc1.x);
    acc0.y = fmaf(p0, h0.y, acc0.y); acc1.y = fmaf(p1, h1.y, acc1.y);
    acc0.z = fmaf(p0, h0.z, acc0.z); acc1.z = fmaf(p1, h1.z, acc1.z);
    acc0.w = fmaf(p0, h0.w, acc0.w); acc1.w = fmaf(p1, h1.w, acc1.w);
  }
  if (j <= n) {
    float p0 = p_lds[wv][j][head];
    int s0 = s_lds[wv][j];
    float4 h0 = *(const float4*)&h[(size_t)s0 * 256 + c0];
    acc0.x = fmaf(p0, h0.x, acc0.x);
    acc0.y = fmaf(p0, h0.y, acc0.y);
    acc0.z = fmaf(p0, h0.z, acc0.z);
    acc0.w = fmaf(p0, h0.w, acc0.w);
  }
  const float4 b4 = *(const float4*)&bias[c0];
  float4 o;
  o.x = fmaxf(fmaf(acc0.x + acc1.x, linv, b4.x), 0.f);
  o.y = fmaxf(fmaf(acc0.y + acc1.y, linv, b4.y), 0.f);
  o.z = fmaxf(fmaf(acc0.z + acc1.z, linv, b4.z), 0.f);
  o.w = fmaxf(fmaf(acc0.w + acc1.w, linv, b4.w), 0.f);
  *(float4*)&feat[(size_t)node * 256 + c0] = o;
}

// ---- BN stats: 1024 blocks x 64 thr (chunk x 4 col-groups).  Each column
// still summed by ONE thread over the same 128 rows in the same order ->
// bit-identical psum/psq; 4x resident waves hide the f64 chain latency. ----
__global__ __launch_bounds__(64) void k_bn_partial(const float* __restrict__ feat,
                                                   double* __restrict__ psum,
                                                   double* __restrict__ psq) {
  const int chunk = blockIdx.x >> 2;
  const int c = (blockIdx.x & 3) * 64 + threadIdx.x;
  const int r0 = chunk * 128;
  double s = 0.0, q = 0.0;
  for (int i = 0; i < 128; i++) {
    double v = (double)feat[(size_t)(r0 + i) * 256 + c];
    s += v;
    q += v * v;
  }
  psum[chunk * 256 + c] = s;
  psq[chunk * 256 + c] = q;
}

// cA/cB for output BN; sv[c]=cA*pwn, sv[256]=sum(cB*pwn) for the score
__global__ __launch_bounds__(1024) void k_bn_final(
    const double* __restrict__ psum, const double* __restrict__ psq,
    const float* __restrict__ gam, const float* __restrict__ bet,
    const float* __restrict__ pw, float* __restrict__ cA, float* __restrict__ cB,
    float* __restrict__ sv) {
  __shared__ double reds[4][256];
  __shared__ double redq[4][256];
  __shared__ double wsq[256];
  __shared__ double sb[256];
  const int t = threadIdx.x;
  const int c = t & 255, sl = t >> 8;
  double s = 0.0, q = 0.0;
  for (int i = sl * 64; i < sl * 64 + 64; i++) {
    s += psum[i * 256 + c];
    q += psq[i * 256 + c];
  }
  reds[sl][c] = s;
  redq[sl][c] = q;
  if (sl == 0) {
    double w = (double)pw[c];
    wsq[c] = w * w;
  }
  __syncthreads();
  if (t == 0) {
    double nn = 0.0;
    for (int i = 0; i < 256; i++) nn += wsq[i];
    wsq[0] = sqrt(nn);
  }
  __syncthreads();
  if (sl == 0) {
    s = reds[0][c] + reds[1][c] + reds[2][c] + reds[3][c];
    q = redq[0][c] + redq[1][c] + redq[2][c] + redq[3][c];
    double mean = s / (double)N_NODES;
    double var = q / (double)N_NODES - mean * mean;
    double a = (double)gam[c] / sqrt(var + 1e-5);
    double cb = (double)bet[c] - mean * a;
    cA[c] = (float)a;
    cB[c] = (float)cb;
    double pwnv = (double)pw[c] / wsq[0];
    sv[c] = (float)(a * pwnv);
    sb[c] = cb * pwnv;
  }
  __syncthreads();
  if (t == 0) {
    double s0 = 0.0;
    for (int i = 0; i < 256; i++) s0 += sb[i];
    sv[256] = (float)s0;
  }
}

// ---- score: one wave per node, coalesced ----
__global__ __launch_bounds__(256) void k_score(
    const float* __restrict__ feat, const float* __restrict__ sv,
    float* __restrict__ score) {
  const int lane = threadIdx.x & 63;
  const int node = blockIdx.x * 4 + (threadIdx.x >> 6);
  const int c0 = lane * 4;
  float4 f = *(const float4*)&feat[(size_t)node * 256 + c0];
  float4 w = *(const float4*)&sv[c0];
  float p = f.x * w.x + f.y * w.y + f.z * w.z + f.w * w.w;
#pragma unroll
  for (int d = 1; d < 64; d <<= 1) p += __shfl_xor(p, d, 64);
  if (lane == 0) score[node] = p + sv[256];
}

// ---- topk + gather: 8 blocks per graph, 64 nodes each ----
__global__ __launch_bounds__(256) void k_topk(
    const float* __restrict__ score, const float* __restrict__ feat,
    const float* __restrict__ cA, const float* __restrict__ cB,
    float* __restrict__ out) {
  __shared__ float ss[NPG];
  __shared__ int rnk[64];
  __shared__ float gt[64];
  const int g = blockIdx.x >> 3;
  const int part = blockIdx.x & 7;
  const int t = threadIdx.x;
  ss[t] = score[g * NPG + t];
  ss[t + 256] = score[g * NPG + t + 256];
  __syncthreads();
  const int ln = t & 3;
  const int ndl = part * 64 + (t >> 2);
  const float s = ss[ndl];
  int rank = 0;
  for (int j = ln * 128; j < ln * 128 + 128; j++) {
    float sj = ss[j];
    rank += (sj > s || (sj == s && j < ndl)) ? 1 : 0;
  }
  rank += __shfl_xor(rank, 1);
  rank += __shfl_xor(rank, 2);
  if (ln == 0) {
    rnk[t >> 2] = rank;
    gt[t >> 2] = tanhf(s);
  }
  __syncthreads();
  for (int idx = t; idx < 64 * 64; idx += 256) {
    int r = idx >> 6;
    int rank2 = rnk[r];
    if (rank2 < KKEEP) {
      int c4 = (idx & 63) * 4;
      int node = g * NPG + part * 64 + r;
      float4 f = *(const float4*)&feat[(size_t)node * 256 + c4];
      float4 a = *(const float4*)&cA[c4];
      float4 b = *(const float4*)&cB[c4];
      float tg = gt[r];
      float4 o;
      o.x = fmaf(f.x, a.x, b.x) * tg;
      o.y = fmaf(f.y, a.y, b.y) * tg;
      o.z = fmaf(f.z, a.z, b.z) * tg;
      o.w = fmaf(f.w, a.w, b.w) * tg;
      *(float4*)&out[(size_t)(g * KKEEP + rank2) * 256 + c4] = o;
    }
  }
}

extern "C" void kernel_launch(void* const* d_in, const int* in_sizes, int n_in,
                              void* d_out, int out_size, void* d_ws, size_t ws_size,
                              hipStream_t stream) {
  const float* x    = (const float*)d_in[0];
  const int*   ei   = (const int*)d_in[1];
  const float* W    = (const float*)d_in[2];
  const float* attS = (const float*)d_in[3];
  const float* attD = (const float*)d_in[4];
  const float* bias = (const float*)d_in[5];
  const float* gam  = (const float*)d_in[6];
  const float* bet  = (const float*)d_in[7];
  const float* pw   = (const float*)d_in[8];
  float* out = (float*)d_out;
  const int E = in_sizes[1] / 2;

  char* p = (char*)d_ws;
  float* h     = (float*)p; p += (size_t)N_NODES * 256 * 4;
  float* feat  = (float*)p; p += (size_t)N_NODES * 256 * 4;
  float* a_src = (float*)p; p += (size_t)N_NODES * 4 * 4;
  float* a_dst = (float*)p; p += (size_t)N_NODES * 4 * 4;
  float* score = (float*)p; p += (size_t)N_NODES * 4;
  double* psum = (double*)p; p += (size_t)256 * 256 * 8;
  double* psq  = (double*)p; p += (size_t)256 * 256 * 8;
  float* cA    = (float*)p; p += 256 * 4;
  float* cB    = (float*)p; p += 256 * 4;
  float* sv    = (float*)p; p += 260 * 4;
  unsigned short* wth  = (unsigned short*)p; p += (size_t)256 * 256 * 2;
  unsigned short* wtl  = (unsigned short*)p; p += (size_t)256 * 256 * 2;
  unsigned short* wtll = (unsigned short*)p; p += (size_t)256 * 256 * 2;
  int* cnt     = (int*)p;   p += (size_t)N_NODES * 4;
  unsigned short* nbr = (unsigned short*)p; p += (size_t)N_NODES * CAP * 2;

  k_conv<<<96, 256, 0, stream>>>(W, wth, wtl, wtll, cnt);
  k_gemm_hist<<<2560, 256, 0, stream>>>(x, wth, wtl, wtll, attS, attD,
                                        h, a_src, a_dst, ei, E, cnt, nbr);
  k_agg<<<N_NODES / 4, 256, 0, stream>>>(h, a_src, a_dst, cnt, nbr, bias, feat);
  k_bn_partial<<<1024, 64, 0, stream>>>(feat, psum, psq);
  k_bn_final<<<1, 1024, 0, stream>>>(psum, psq, gam, bet, pw, cA, cB, sv);
  k_score<<<N_NODES / 4, 256, 0, stream>>>(feat, sv, score);
  k_topk<<<NGRAPH * 8, 256, 0, stream>>>(score, feat, cA, cB, out);
}

// Round 10
// 203.671 us; speedup vs baseline: 1.0835x; 1.0114x over previous
//
#include <hip/hip_runtime.h>
#include <math.h>

#define N_NODES 32768
#define NPG 512
#define NGRAPH 64
#define KKEEP 256
#define CAP 64

typedef __attribute__((ext_vector_type(8))) short short8;
typedef __attribute__((ext_vector_type(4))) float f32x4;

__device__ __forceinline__ unsigned short f2bf(float v) {
  unsigned u = __builtin_bit_cast(unsigned, v);
  u = (u + 0x7FFFu + ((u >> 16) & 1u)) >> 16;
  return (unsigned short)u;
}
__device__ __forceinline__ float bf2f(unsigned short u) {
  unsigned v = ((unsigned)u) << 16;
  return __builtin_bit_cast(float, v);
}

__device__ __forceinline__ void async_cp16(unsigned short* l, const unsigned short* g) {
  __builtin_amdgcn_global_load_lds(
      (const __attribute__((address_space(1))) unsigned int*)g,
      (__attribute__((address_space(3))) unsigned int*)l, 16, 0, 0);
}

// raw barrier: memory-clobber asm (blocks IR-level motion) + sched_barrier
// (blocks MIR-level motion, rule 18).  No implicit vmcnt(0) drain.
__device__ __forceinline__ void block_barrier() {
  __builtin_amdgcn_sched_barrier(0);
  asm volatile("s_barrier" ::: "memory");
  __builtin_amdgcn_sched_barrier(0);
}
__device__ __forceinline__ void wait_all() {
  asm volatile("s_waitcnt vmcnt(0) lgkmcnt(0)" ::: "memory");
  __builtin_amdgcn_sched_barrier(0);
}

// ---- W split-3 bf16 convert + cnt zeroing (blocks 64..95) [r9-verified] ----
__global__ __launch_bounds__(256) void k_conv(
    const float* __restrict__ W,
    unsigned short* __restrict__ wth, unsigned short* __restrict__ wtl,
    unsigned short* __restrict__ wtll, int* __restrict__ cnt) {
  const int t = threadIdx.x;
  if (blockIdx.x >= 64) {
    int i = (blockIdx.x - 64) * 1024 + t * 4;
    *(int4*)&cnt[i] = make_int4(0, 0, 0, 0);
    return;
  }
  int n = blockIdx.x * 4 + (t >> 6);         // output col of W
  int k = (t & 63) * 4;
  unsigned short hb[4], lb[4], qb[4];
#pragma unroll
  for (int j = 0; j < 4; j++) {
    float v = W[(size_t)(k + j) * 256 + n];
    unsigned short hh = f2bf(v);
    float e1 = v - bf2f(hh);                 // exact
    unsigned short ll = f2bf(e1);
    float e2 = e1 - bf2f(ll);                // exact
    hb[j] = hh; lb[j] = ll; qb[j] = f2bf(e2);
  }
  *(uint2*)&wth[(size_t)n * 256 + k] = *(uint2*)&hb[0];
  *(uint2*)&wtl[(size_t)n * 256 + k] = *(uint2*)&lb[0];
  *(uint2*)&wtll[(size_t)n * 256 + k] = *(uint2*)&qb[0];
}

// ---- merged: pipelined MFMA split-3 GEMM (blocks 0..511, 128x128, 512 thr)
//      + edge bucketing (blocks 512..1535)  [round-6 VERBATIM: 52.6 us] ----
#define A_STR 129
#define A_SZ 12384             // ushort: 3 planes x 4*129*8
#define B_BASE 12384           // ushort
#define B_SZ 12288             // ushort: 3 planes x 4096
__global__ __launch_bounds__(512, 4) void k_gemm_hist(
    const float* __restrict__ x,
    const unsigned short* __restrict__ wth, const unsigned short* __restrict__ wtl,
    const unsigned short* __restrict__ wtll,
    const float* __restrict__ attS, const float* __restrict__ attD,
    float* __restrict__ h, float* __restrict__ a_src, float* __restrict__ a_dst,
    const int* __restrict__ ei, int E, int* __restrict__ cnt,
    unsigned short* __restrict__ nbr) {
  __shared__ unsigned short lds[36960];      // 73,920 B
  const int t = threadIdx.x;
  const int bid = blockIdx.x;
  if (bid >= 512) {
    // edge bucketing: independent of GEMM, backfills behind it
    int e = (bid - 512) * 512 + t;
    if (e < E) {
      int s = ei[e];
      int d = ei[E + e];
      int slot = atomicAdd(&cnt[d], 1);
      if (slot < CAP) nbr[(size_t)d * CAP + slot] = (unsigned short)(s & (NPG - 1));
    }
    return;
  }
  // XCD pairing: both nh halves of an mb land on the same XCD (bid%8);
  // XCD c owns mb in [32c, 32c+32) -> A rows [4096c, 4096c+4096), matches k_agg.
  const int mb = (bid & 7) * 32 + (bid >> 4);
  const int nh = (bid >> 3) & 1;
  const int row0 = mb * 128;
  const int wid = t >> 6, lane = t & 63;
  const int q = lane >> 4, ln = lane & 15;
  const int wm = (wid >> 1) * 32, wn = (wid & 1) * 64;
  const int sr = t >> 2, scq = t & 3;        // A staging: 128 rows x 4 k-octs
  f32x4 acc[2][4] = {};

  // ---- prologue: stage kc=0 ----
  {
    size_t ga = (size_t)(row0 + sr) * 256 + scq * 8;
    float4 f0 = *(const float4*)&x[ga];
    float4 f1 = *(const float4*)&x[ga + 4];
    float ff[8] = {f0.x, f0.y, f0.z, f0.w, f1.x, f1.y, f1.z, f1.w};
    unsigned short hs[8], ls[8], qs[8];
#pragma unroll
    for (int j = 0; j < 8; j++) {
      unsigned short hh = f2bf(ff[j]);
      float e1 = ff[j] - bf2f(hh);
      unsigned short ll = f2bf(e1);
      float e2 = e1 - bf2f(ll);
      hs[j] = hh; ls[j] = ll; qs[j] = f2bf(e2);
    }
    *(uint4*)&lds[((0 * 4 + scq) * A_STR + sr) * 8] = *(uint4*)&hs[0];
    *(uint4*)&lds[((1 * 4 + scq) * A_STR + sr) * 8] = *(uint4*)&ls[0];
    *(uint4*)&lds[((2 * 4 + scq) * A_STR + sr) * 8] = *(uint4*)&qs[0];
    size_t gb = (size_t)(nh * 128 + (t & 127)) * 256 + (t >> 7) * 8;
    async_cp16(&lds[B_BASE + 0 * 4096 + t * 8], &wth[gb]);
    async_cp16(&lds[B_BASE + 1 * 4096 + t * 8], &wtl[gb]);
    async_cp16(&lds[B_BASE + 2 * 4096 + t * 8], &wtll[gb]);
  }
  wait_all();
  block_barrier();

  for (int kc = 0; kc < 8; kc++) {
    const int cur = kc & 1;
    // issue next-tile loads FIRST (in flight across the whole MFMA phase)
    float4 f0, f1;
    if (kc < 7) {
      const int k1 = (kc + 1) * 32;
      size_t ga = (size_t)(row0 + sr) * 256 + k1 + scq * 8;
      f0 = *(const float4*)&x[ga];
      f1 = *(const float4*)&x[ga + 4];
      unsigned short* bb = &lds[B_BASE + (cur ^ 1) * B_SZ];
      size_t gb = (size_t)(nh * 128 + (t & 127)) * 256 + k1 + (t >> 7) * 8;
      async_cp16(&bb[0 * 4096 + t * 8], &wth[gb]);
      async_cp16(&bb[1 * 4096 + t * 8], &wtl[gb]);
      async_cp16(&bb[2 * 4096 + t * 8], &wtll[gb]);
    }
    // compute on buf[cur]
    const unsigned short* bc = &lds[B_BASE + cur * B_SZ];
    short8 ah[2], al[2], aq[2];
#pragma unroll
    for (int mt = 0; mt < 2; mt++) {
      int r = wm + mt * 16 + ln;
      ah[mt] = *(const short8*)&lds[((0 * 4 + q) * A_STR + r) * 8];
      al[mt] = *(const short8*)&lds[((1 * 4 + q) * A_STR + r) * 8];
      aq[mt] = *(const short8*)&lds[((2 * 4 + q) * A_STR + r) * 8];
    }
#pragma unroll
    for (int nt = 0; nt < 4; nt++) {
      int r = wn + nt * 16 + ln;
      short8 bh = *(const short8*)&bc[0 * 4096 + (q * 128 + r) * 8];
      short8 bl = *(const short8*)&bc[1 * 4096 + (q * 128 + r) * 8];
      short8 bq = *(const short8*)&bc[2 * 4096 + (q * 128 + r) * 8];
#pragma unroll
      for (int mt = 0; mt < 2; mt++) {
        acc[mt][nt] = __builtin_amdgcn_mfma_f32_16x16x32_bf16(ah[mt], bh, acc[mt][nt], 0, 0, 0);
        acc[mt][nt] = __builtin_amdgcn_mfma_f32_16x16x32_bf16(ah[mt], bl, acc[mt][nt], 0, 0, 0);
        acc[mt][nt] = __builtin_amdgcn_mfma_f32_16x16x32_bf16(al[mt], bh, acc[mt][nt], 0, 0, 0);
        acc[mt][nt] = __builtin_amdgcn_mfma_f32_16x16x32_bf16(ah[mt], bq, acc[mt][nt], 0, 0, 0);
        acc[mt][nt] = __builtin_amdgcn_mfma_f32_16x16x32_bf16(al[mt], bl, acc[mt][nt], 0, 0, 0);
        acc[mt][nt] = __builtin_amdgcn_mfma_f32_16x16x32_bf16(aq[mt], bh, acc[mt][nt], 0, 0, 0);
      }
    }
    // convert next A while B(kc+1) is still in flight
    unsigned short hs[8], ls[8], qs[8];
    if (kc < 7) {
      float ff[8] = {f0.x, f0.y, f0.z, f0.w, f1.x, f1.y, f1.z, f1.w};
#pragma unroll
      for (int j = 0; j < 8; j++) {
        unsigned short hh = f2bf(ff[j]);
        float e1 = ff[j] - bf2f(hh);
        unsigned short ll = f2bf(e1);
        float e2 = e1 - bf2f(ll);
        hs[j] = hh; ls[j] = ll; qs[j] = f2bf(e2);
      }
    }
    block_barrier();            // all waves done READING the A buffer
    if (kc < 7) {
      *(uint4*)&lds[((0 * 4 + scq) * A_STR + sr) * 8] = *(uint4*)&hs[0];
      *(uint4*)&lds[((1 * 4 + scq) * A_STR + sr) * 8] = *(uint4*)&ls[0];
      *(uint4*)&lds[((2 * 4 + scq) * A_STR + sr) * 8] = *(uint4*)&qs[0];
    }
    wait_all();                 // A writes visible; B(kc+1) landed (issued early)
    block_barrier();
  }

  // epilogue: store h; att partials via LDS transpose (aliased over staging).
  // XOR swizzle (ln^(q*4)) is bijective per row; read back in ln order ->
  // bit-identical sums to the round-0 epilogue.
  const int head = nh * 2 + (wid & 1);
  float sA[4], sD[4];
#pragma unroll
  for (int nt = 0; nt < 4; nt++) {
    int n = nh * 128 + wn + nt * 16 + ln;
    sA[nt] = attS[n];
    sD[nt] = attD[n];
  }
  float2* epi = (float2*)lds;   // [wid(8)][q(4)][row(8)][18] float2
#pragma unroll
  for (int mt = 0; mt < 2; mt++) {
#pragma unroll
    for (int reg = 0; reg < 4; reg++) {
      int m = row0 + wm + mt * 16 + q * 4 + reg;
      float ps = 0.f, pd = 0.f;
#pragma unroll
      for (int nt = 0; nt < 4; nt++) {
        float v = acc[mt][nt][reg];
        h[(size_t)m * 256 + nh * 128 + wn + nt * 16 + ln] = v;
        ps = fmaf(v, sA[nt], ps);
        pd = fmaf(v, sD[nt], pd);
      }
      epi[(((wid * 4 + q) * 8) + mt * 4 + reg) * 18 + (ln ^ (q * 4))] =
          make_float2(ps, pd);
    }
  }
  __syncthreads();
  if (lane < 32) {
    const int rr2 = lane & 7;                // mt*4+reg
    const int q2 = lane >> 3;                // row group's q
    const int base = (((wid * 4 + q2) * 8) + rr2) * 18;
    float ps = 0.f, pd = 0.f;
#pragma unroll
    for (int i = 0; i < 16; i++) {
      float2 v = epi[base + (i ^ (q2 * 4))];
      ps += v.x;
      pd += v.y;
    }
    int m = row0 + wm + (rr2 >> 2) * 16 + q2 * 4 + (rr2 & 3);
    a_src[m * 4 + head] = ps;
    a_dst[m * 4 + head] = pd;
  }
}

// ---- aggregation: softmax weights computed once, broadcast via LDS ----
__global__ __launch_bounds__(256) void k_agg(
    const float* __restrict__ h, const float* __restrict__ a_src,
    const float* __restrict__ a_dst, const int* __restrict__ cnt,
    const unsigned short* __restrict__ nbr, const float* __restrict__ bias,
    float* __restrict__ feat) {
  __shared__ float p_lds[4][68][4];
  __shared__ int s_lds[4][68];
  const int wv = threadIdx.x >> 6;
  const int lane = threadIdx.x & 63;
  int nb = (blockIdx.x & 7) * (N_NODES / 4 / 8) + (blockIdx.x >> 3);
  const int node = nb * 4 + wv;
  const int head = lane >> 4;
  const int li = lane & 15;
  const int c0 = lane * 4;
  const int base = node & ~(NPG - 1);
  const float ad = a_dst[node * 4 + head];
  int n = cnt[node];
  if (n > CAP) n = CAP;
  float e_reg[5];
  int srcs[5];
  int nit = 0;
  float m = -1e30f;
  for (int j = li; j <= n; j += 16) {
    int s = (j < n) ? base + (int)nbr[(size_t)node * CAP + j] : node;
    float e = a_src[s * 4 + head] + ad;
    e = (e > 0.f) ? e : 0.2f * e;
    srcs[nit] = s;
    e_reg[nit++] = e;
    m = fmaxf(m, e);
  }
#pragma unroll
  for (int d = 1; d < 16; d <<= 1) m = fmaxf(m, __shfl_xor(m, d, 16));
  float l = 0.f;
  for (int i = 0; i < nit; i++) {
    int j = li + i * 16;
    float p = __expf(e_reg[i] - m);
    l += p;
    p_lds[wv][j][head] = p;
    if (head == 0) s_lds[wv][j] = srcs[i];
  }
#pragma unroll
  for (int d = 1; d < 16; d <<= 1) l += __shfl_xor(l, d, 16);
  const float linv = 1.f / (l + 1e-16f);
  __builtin_amdgcn_s_waitcnt(0);
  float4 acc0 = make_float4(0.f, 0.f, 0.f, 0.f);
  float4 acc1 = make_float4(0.f, 0.f, 0.f, 0.f);
  int j = 0;
  for (; j + 1 <= n; j += 2) {
    float p0 = p_lds[wv][j][head];
    float p1 = p_lds[wv][j + 1][head];
    int s0 = s_lds[wv][j];
    int s1 = s_lds[wv][j + 1];
    float4 h0 = *(const float4*)&h[(size_t)s0 * 256 + c0];
    float4 h1 = *(const float4*)&h[(size_t)s1 * 256 + c0];
    acc0.x = fmaf(p0, h0.x, acc0.x); acc1.x = fmaf(p1, h1.x, acc1.x);
    acc0.y = fmaf(p0, h0.y, acc0.y); acc1.y = fmaf(p1, h1.y, acc1.y);
    acc0.z = fmaf(p0, h0.z, acc0.z); acc1.z = fmaf(p1, h1.z, acc1.z);
    acc0.w = fmaf(p0, h0.w, acc0.w); acc1.w = fmaf(p1, h1.w, acc1.w);
  }
  if (j <= n) {
    float p0 = p_lds[wv][j][head];
    int s0 = s_lds[wv][j];
    float4 h0 = *(const float4*)&h[(size_t)s0 * 256 + c0];
    acc0.x = fmaf(p0, h0.x, acc0.x);
    acc0.y = fmaf(p0, h0.y, acc0.y);
    acc0.z = fmaf(p0, h0.z, acc0.z);
    acc0.w = fmaf(p0, h0.w, acc0.w);
  }
  const float4 b4 = *(const float4*)&bias[c0];
  float4 o;
  o.x = fmaxf(fmaf(acc0.x + acc1.x, linv, b4.x), 0.f);
  o.y = fmaxf(fmaf(acc0.y + acc1.y, linv, b4.y), 0.f);
  o.z = fmaxf(fmaf(acc0.z + acc1.z, linv, b4.z), 0.f);
  o.w = fmaxf(fmaf(acc0.w + acc1.w, linv, b4.w), 0.f);
  *(float4*)&feat[(size_t)node * 256 + c0] = o;
}

// ---- BN stats: 1024 blocks x 64 thr (chunk x 4 col-groups) [r9-verified:
// each column still summed by ONE thread over the same 128 rows in the same
// order -> bit-identical psum/psq; 4x resident waves hide f64 latency] ----
__global__ __launch_bounds__(64) void k_bn_partial(const float* __restrict__ feat,
                                                   double* __restrict__ psum,
                                                   double* __restrict__ psq) {
  const int chunk = blockIdx.x >> 2;
  const int c = (blockIdx.x & 3) * 64 + threadIdx.x;
  const int r0 = chunk * 128;
  double s = 0.0, q = 0.0;
  for (int i = 0; i < 128; i++) {
    double v = (double)feat[(size_t)(r0 + i) * 256 + c];
    s += v;
    q += v * v;
  }
  psum[chunk * 256 + c] = s;
  psq[chunk * 256 + c] = q;
}

// cA/cB for output BN; sv[c]=cA*pwn, sv[256]=sum(cB*pwn) for the score
__global__ __launch_bounds__(1024) void k_bn_final(
    const double* __restrict__ psum, const double* __restrict__ psq,
    const float* __restrict__ gam, const float* __restrict__ bet,
    const float* __restrict__ pw, float* __restrict__ cA, float* __restrict__ cB,
    float* __restrict__ sv) {
  __shared__ double reds[4][256];
  __shared__ double redq[4][256];
  __shared__ double wsq[256];
  __shared__ double sb[256];
  const int t = threadIdx.x;
  const int c = t & 255, sl = t >> 8;
  double s = 0.0, q = 0.0;
  for (int i = sl * 64; i < sl * 64 + 64; i++) {
    s += psum[i * 256 + c];
    q += psq[i * 256 + c];
  }
  reds[sl][c] = s;
  redq[sl][c] = q;
  if (sl == 0) {
    double w = (double)pw[c];
    wsq[c] = w * w;
  }
  __syncthreads();
  if (t == 0) {
    double nn = 0.0;
    for (int i = 0; i < 256; i++) nn += wsq[i];
    wsq[0] = sqrt(nn);
  }
  __syncthreads();
  if (sl == 0) {
    s = reds[0][c] + reds[1][c] + reds[2][c] + reds[3][c];
    q = redq[0][c] + redq[1][c] + redq[2][c] + redq[3][c];
    double mean = s / (double)N_NODES;
    double var = q / (double)N_NODES - mean * mean;
    double a = (double)gam[c] / sqrt(var + 1e-5);
    double cb = (double)bet[c] - mean * a;
    cA[c] = (float)a;
    cB[c] = (float)cb;
    double pwnv = (double)pw[c] / wsq[0];
    sv[c] = (float)(a * pwnv);
    sb[c] = cb * pwnv;
  }
  __syncthreads();
  if (t == 0) {
    double s0 = 0.0;
    for (int i = 0; i < 256; i++) s0 += sb[i];
    sv[256] = (float)s0;
  }
}

// ---- score: one wave per node, coalesced ----
__global__ __launch_bounds__(256) void k_score(
    const float* __restrict__ feat, const float* __restrict__ sv,
    float* __restrict__ score) {
  const int lane = threadIdx.x & 63;
  const int node = blockIdx.x * 4 + (threadIdx.x >> 6);
  const int c0 = lane * 4;
  float4 f = *(const float4*)&feat[(size_t)node * 256 + c0];
  float4 w = *(const float4*)&sv[c0];
  float p = f.x * w.x + f.y * w.y + f.z * w.z + f.w * w.w;
#pragma unroll
  for (int d = 1; d < 64; d <<= 1) p += __shfl_xor(p, d, 64);
  if (lane == 0) score[node] = p + sv[256];
}

// ---- topk + gather: 8 blocks per graph, 64 nodes each ----
__global__ __launch_bounds__(256) void k_topk(
    const float* __restrict__ score, const float* __restrict__ feat,
    const float* __restrict__ cA, const float* __restrict__ cB,
    float* __restrict__ out) {
  __shared__ float ss[NPG];
  __shared__ int rnk[64];
  __shared__ float gt[64];
  const int g = blockIdx.x >> 3;
  const int part = blockIdx.x & 7;
  const int t = threadIdx.x;
  ss[t] = score[g * NPG + t];
  ss[t + 256] = score[g * NPG + t + 256];
  __syncthreads();
  const int ln = t & 3;
  const int ndl = part * 64 + (t >> 2);
  const float s = ss[ndl];
  int rank = 0;
  for (int j = ln * 128; j < ln * 128 + 128; j++) {
    float sj = ss[j];
    rank += (sj > s || (sj == s && j < ndl)) ? 1 : 0;
  }
  rank += __shfl_xor(rank, 1);
  rank += __shfl_xor(rank, 2);
  if (ln == 0) {
    rnk[t >> 2] = rank;
    gt[t >> 2] = tanhf(s);
  }
  __syncthreads();
  for (int idx = t; idx < 64 * 64; idx += 256) {
    int r = idx >> 6;
    int rank2 = rnk[r];
    if (rank2 < KKEEP) {
      int c4 = (idx & 63) * 4;
      int node = g * NPG + part * 64 + r;
      float4 f = *(const float4*)&feat[(size_t)node * 256 + c4];
      float4 a = *(const float4*)&cA[c4];
      float4 b = *(const float4*)&cB[c4];
      float tg = gt[r];
      float4 o;
      o.x = fmaf(f.x, a.x, b.x) * tg;
      o.y = fmaf(f.y, a.y, b.y) * tg;
      o.z = fmaf(f.z, a.z, b.z) * tg;
      o.w = fmaf(f.w, a.w, b.w) * tg;
      *(float4*)&out[(size_t)(g * KKEEP + rank2) * 256 + c4] = o;
    }
  }
}

extern "C" void kernel_launch(void* const* d_in, const int* in_sizes, int n_in,
                              void* d_out, int out_size, void* d_ws, size_t ws_size,
                              hipStream_t stream) {
  const float* x    = (const float*)d_in[0];
  const int*   ei   = (const int*)d_in[1];
  const float* W    = (const float*)d_in[2];
  const float* attS = (const float*)d_in[3];
  const float* attD = (const float*)d_in[4];
  const float* bias = (const float*)d_in[5];
  const float* gam  = (const float*)d_in[6];
  const float* bet  = (const float*)d_in[7];
  const float* pw   = (const float*)d_in[8];
  float* out = (float*)d_out;
  const int E = in_sizes[1] / 2;

  char* p = (char*)d_ws;
  float* h     = (float*)p; p += (size_t)N_NODES * 256 * 4;
  float* feat  = (float*)p; p += (size_t)N_NODES * 256 * 4;
  float* a_src = (float*)p; p += (size_t)N_NODES * 4 * 4;
  float* a_dst = (float*)p; p += (size_t)N_NODES * 4 * 4;
  float* score = (float*)p; p += (size_t)N_NODES * 4;
  double* psum = (double*)p; p += (size_t)256 * 256 * 8;
  double* psq  = (double*)p; p += (size_t)256 * 256 * 8;
  float* cA    = (float*)p; p += 256 * 4;
  float* cB    = (float*)p; p += 256 * 4;
  float* sv    = (float*)p; p += 260 * 4;
  unsigned short* wth  = (unsigned short*)p; p += (size_t)256 * 256 * 2;
  unsigned short* wtl  = (unsigned short*)p; p += (size_t)256 * 256 * 2;
  unsigned short* wtll = (unsigned short*)p; p += (size_t)256 * 256 * 2;
  int* cnt     = (int*)p;   p += (size_t)N_NODES * 4;
  unsigned short* nbr = (unsigned short*)p; p += (size_t)N_NODES * CAP * 2;

  k_conv<<<96, 256, 0, stream>>>(W, wth, wtl, wtll, cnt);
  k_gemm_hist<<<1536, 512, 0, stream>>>(x, wth, wtl, wtll, attS, attD,
                                        h, a_src, a_dst, ei, E, cnt, nbr);
  k_agg<<<N_NODES / 4, 256, 0, stream>>>(h, a_src, a_dst, cnt, nbr, bias, feat);
  k_bn_partial<<<1024, 64, 0, stream>>>(feat, psum, psq);
  k_bn_final<<<1, 1024, 0, stream>>>(psum, psq, gam, bet, pw, cA, cB, sv);
  k_score<<<N_NODES / 4, 256, 0, stream>>>(feat, sv, score);
  k_topk<<<NGRAPH * 8, 256, 0, stream>>>(score, feat, cA, cB, out);
}